// Round 6
// baseline (548.417 us; speedup 1.0000x reference)
//
#include <hip/hip_runtime.h>
#include <hip/hip_bf16.h>
#include <float.h>

#define BATCHES 256
#define NPB     512            // nodes per batch
#define NN      (BATCHES*NPB)  // 131072 total nodes
#define KNN     16
#define KP      17
#define DIN     32
#define DH      128
#define DOUT    8
#define BUFS    24             // phase-2 collection slots per thread
#define REVC    96             // reverse capacity: 2-D kNN in-degree bound 6K=96

// ---------------------------------------------------------------- KNN
// 4 threads/node, each scans a disjoint 128-candidate quarter.
// P1: top-17 d2 values via pair bubble (min, v_med3, max). Exact arith.
// thr: PAIR-local exact 17th-smallest d2 of the pair's 256 candidates
//      (half-clean max) -> per-lane collection <= 17 <= BUFS guaranteed.
// P2: collect j with max(d2,0) <= max(thr2,0) into LDS (u16).
// Final: both pair lanes run the exact lex (dist,idx) chain over the
//      pair's two buffers in ascending-j order (identical sorted lists),
//      then ONE canonical cross-pair half-clean + minpos + quad emit.
// Edges scatter directly into fixed-capacity reverse lists.
__global__ __launch_bounds__(256) void knn_kernel(
    const float* __restrict__ obs, int* __restrict__ fill, int* __restrict__ rev) {
  __shared__ float4 cand[NPB];                 // {x, y, sq, -}  8 KiB
  __shared__ unsigned short buf[256 * BUFS];   // 12 KiB
  const int b = blockIdx.x >> 3;               // 8 blocks per batch
  const int oct = blockIdx.x & 7;
  const int tid = threadIdx.x;
  const int part = tid & 3;                    // candidate quarter owned
  const int nl = (tid >> 2) + oct * 64;        // local node id

  for (int l = tid; l < NPB; l += 256) {
    const float* orow = obs + ((size_t)b * NPB + l) * DIN;
    const float xx = orow[0], yy = orow[1];
    const float sq = __fadd_rn(__fmul_rn(xx, xx), __fmul_rn(yy, yy));
    cand[l] = make_float4(xx, yy, sq, 0.0f);
  }
  __syncthreads();

  const float4 me = cand[nl];
  const float x = me.x, y = me.y, s = me.z;
  const int jbase = part * 128;

  // ---------- phase 1: top-17 d2 of own 128, 2 candidates per pass
  float dl[KP];
#pragma unroll
  for (int t = 0; t < KP; ++t) dl[t] = FLT_MAX;

  for (int jj = 0; jj < 128; jj += 2) {
    const float4 ca = cand[jbase + jj];
    const float4 cb = cand[jbase + jj + 1];
    const float dota = __fadd_rn(__fmul_rn(x, ca.x), __fmul_rn(y, ca.y));
    const float d2a  = __fsub_rn(__fadd_rn(s, ca.z), __fmul_rn(2.0f, dota));
    const float dotb = __fadd_rn(__fmul_rn(x, cb.x), __fmul_rn(y, cb.y));
    const float d2b  = __fsub_rn(__fadd_rn(s, cb.z), __fmul_rn(2.0f, dotb));
    float c0 = fminf(d2a, d2b);
    float c1 = fmaxf(d2a, d2b);
#pragma unroll
    for (int t = 0; t < KP; ++t) {
      const float mn = fminf(dl[t], c0);
      float mdv;
      asm("v_med3_f32 %0, %1, %2, %3" : "=v"(mdv) : "v"(dl[t]), "v"(c0), "v"(c1));
      c1 = fmaxf(dl[t], c1);
      dl[t] = mn;
      c0 = mdv;
    }
  }

  // ---------- pair-local threshold: exact 17th-smallest d2 of pair union
  float thr2 = -FLT_MAX;
#pragma unroll
  for (int i = 0; i < KP; ++i) {
    const float ob = __shfl_xor(dl[KP - 1 - i], 1);
    thr2 = fmaxf(thr2, fminf(dl[i], ob));
  }
  const float thr2c = fmaxf(thr2, 0.0f);

  // ---------- phase 2: collect own candidates (no sqrt; order-equivalent)
  int cnt = 0;
  const int bufbase = tid * BUFS;
  for (int jj = 0; jj < 128; ++jj) {
    const int j = jbase + jj;
    const float4 c = cand[j];
    const float dot = __fadd_rn(__fmul_rn(x, c.x), __fmul_rn(y, c.y));
    const float d2  = __fsub_rn(__fadd_rn(s, c.z), __fmul_rn(2.0f, dot));
    if (fmaxf(d2, 0.0f) <= thr2c && cnt < BUFS) {
      buf[bufbase + cnt] = (unsigned short)j;
      ++cnt;
    }
  }
  __syncthreads();

  // ---------- final: exact lex (dist,idx) top-17 over the PAIR's items,
  // ascending j (even lane's buffer then odd lane's) -> both pair lanes
  // produce the identical sorted list.
  const int othercnt = __shfl_xor(cnt, 1);
  const int cntE = (tid & 1) ? othercnt : cnt;
  const int cntO = (tid & 1) ? cnt : othercnt;
  const int evenBase = (tid & ~1) * BUFS;
  const int oddBase  = evenBase + BUFS;

  float fd[KP]; int fi[KP];
#pragma unroll
  for (int t = 0; t < KP; ++t) { fd[t] = FLT_MAX; fi[t] = 0x7fffffff; }
  for (int c = 0; c < cntE + cntO; ++c) {
    const int j = (c < cntE) ? buf[evenBase + c] : buf[oddBase + (c - cntE)];
    const float4 pj = cand[j];
    const float dot = __fadd_rn(__fmul_rn(x, pj.x), __fmul_rn(y, pj.y));
    const float d2  = __fsub_rn(__fadd_rn(s, pj.z), __fmul_rn(2.0f, dot));
    const float dc  = sqrtf(fmaxf(d2, 0.0f));
    if (dc < fd[KP - 1]) {
      bool shp = true;
#pragma unroll
      for (int t = KP - 1; t >= 1; --t) {
        const bool sh = dc < fd[t - 1];
        const float nd = sh ? fd[t - 1] : (shp ? dc : fd[t]);
        const int   ni = sh ? fi[t - 1] : (shp ? j  : fi[t]);
        fd[t] = nd; fi[t] = ni;
        shp = sh;
      }
      if (shp) { fd[0] = dc; fi[0] = j; }
    }
  }

  // ---------- canonical cross-pair merge (sorted inputs; R3-verified form)
  const int phalf = (tid >> 1) & 1;   // which pair within the quad
  float Ad[KP], Bd[KP]; int Ai[KP], Bi[KP];
#pragma unroll
  for (int t = 0; t < KP; ++t) {
    const float o_d = __shfl_xor(fd[t], 2);
    const int   o_i = __shfl_xor(fi[t], 2);
    Ad[t] = phalf ? o_d : fd[t];
    Ai[t] = phalf ? o_i : fi[t];
    Bd[t] = phalf ? fd[t] : o_d;
    Bi[t] = phalf ? fi[t] : o_i;
  }
  float md[KP]; int mi[KP];
#pragma unroll
  for (int i = 0; i < KP; ++i) {
    const float da = Ad[i], db = Bd[KP - 1 - i];
    const int   ia = Ai[i], ib = Bi[KP - 1 - i];
    const bool aless = (da < db) || (da == db && ia < ib);
    md[i] = aless ? da : db;
    mi[i] = aless ? ia : ib;
  }
  int minpos = 0;
#pragma unroll
  for (int i = 1; i < KP; ++i) {
    const bool less = (md[i] < md[minpos]) ||
                      (md[i] == md[minpos] && mi[i] < mi[minpos]);
    minpos = less ? i : minpos;
  }
  // emit edges: quad lanes split slots by (i & 3)
  const int src = b * NPB + nl;
#pragma unroll
  for (int i = 0; i < KP; ++i) {
    if ((i & 3) == part && i != minpos) {
      const int g = b * NPB + mi[i];
      const int slot = atomicAdd(&fill[g], 1);
      if (slot < REVC) rev[(size_t)g * REVC + slot] = src;
    }
  }
}

// ---------------------------------------------------------------- GEMM
// Block computes 32 rows x 128 cols. Thread = 4 rows x 4 cols.
// xs consumed via ds_read_b128 (float4) per row-group per 4-k chunk.
// DINV epilogue (layer 1 only): dinv[row] = rsqrt(indeg+1).
template <int KDIM, bool DINV>
__global__ __launch_bounds__(256) void gemm_kernel(
    const float* __restrict__ X, const float* __restrict__ W,
    float* __restrict__ H, const int* __restrict__ fill,
    float* __restrict__ dinv) {
  __shared__ float ws[32][DH];
  __shared__ float xs[32][32];
  const int tid = threadIdx.x;
  const int tx = tid & 31;
  const int ty = tid >> 5;
  const int rowBase = blockIdx.x * 32;
  float acc[4][4] = {};

  for (int kb = 0; kb < KDIM; kb += 32) {
    for (int l = tid; l < 32 * DH / 4; l += 256) {
      const int kk = l >> 5;
      const int cc = (l & 31) * 4;
      const float4 w4 = *(const float4*)&W[(size_t)(kb + kk) * DH + cc];
      *(float4*)&ws[kk][cc] = w4;
    }
    for (int l = tid; l < 32 * 32 / 4; l += 256) {
      const int rr = l >> 3;
      const int kk = (l & 7) * 4;
      const float4 x4 = *(const float4*)&X[((size_t)rowBase + rr) * KDIM + kb + kk];
      *(float4*)&xs[rr][kk] = x4;
    }
    __syncthreads();
#pragma unroll
    for (int k4 = 0; k4 < 8; ++k4) {
      float4 xr[4];
#pragma unroll
      for (int r = 0; r < 4; ++r)
        xr[r] = *(const float4*)&xs[ty * 4 + r][k4 * 4];
#pragma unroll
      for (int kk = 0; kk < 4; ++kk) {
        const float4 w4 = *(const float4*)&ws[k4 * 4 + kk][tx * 4];
        const float a0 = ((const float*)&xr[0])[kk];
        const float a1 = ((const float*)&xr[1])[kk];
        const float a2 = ((const float*)&xr[2])[kk];
        const float a3 = ((const float*)&xr[3])[kk];
        acc[0][0] += a0 * w4.x; acc[0][1] += a0 * w4.y; acc[0][2] += a0 * w4.z; acc[0][3] += a0 * w4.w;
        acc[1][0] += a1 * w4.x; acc[1][1] += a1 * w4.y; acc[1][2] += a1 * w4.z; acc[1][3] += a1 * w4.w;
        acc[2][0] += a2 * w4.x; acc[2][1] += a2 * w4.y; acc[2][2] += a2 * w4.z; acc[2][3] += a2 * w4.w;
        acc[3][0] += a3 * w4.x; acc[3][1] += a3 * w4.y; acc[3][2] += a3 * w4.z; acc[3][3] += a3 * w4.w;
      }
    }
    __syncthreads();
  }
#pragma unroll
  for (int r = 0; r < 4; ++r) {
    const float4 o = make_float4(acc[r][0], acc[r][1], acc[r][2], acc[r][3]);
    *(float4*)&H[((size_t)rowBase + ty * 4 + r) * DH + tx * 4] = o;
  }
  if (DINV && tid < 32) {
    const int node = rowBase + tid;
    dinv[node] = rsqrtf((float)fill[node] + 1.0f);
  }
}

// ------------------------------------------------------------- aggregate
// One wave per node; lane = (edge-parity half, float4 chunk q).
// HEAD=false: write tanh(agg+bias) to Xout.
// HEAD=true:  fused output head: out[v] = tanh(agg+bias) @ Wout + bout.
template <bool HEAD>
__global__ __launch_bounds__(256) void agg_kernel(
    const float* __restrict__ H, const int* __restrict__ fill,
    const int* __restrict__ rev, const float* __restrict__ dinv,
    const float* __restrict__ bias, const float* __restrict__ Wout,
    const float* __restrict__ bout, float* __restrict__ Xout) {
  const int gtid = blockIdx.x * blockDim.x + threadIdx.x;
  const int v = gtid >> 6;
  if (v >= NN) return;
  const int lane = threadIdx.x & 63;
  const int half = lane >> 5;
  const int q = lane & 31;
  const float dv = dinv[v];

  float4 acc = make_float4(0.f, 0.f, 0.f, 0.f);
  if (half == 0) {                     // self term once
    const float4 hs = *((const float4*)(H + (size_t)v * DH) + q);
    const float w = dv * dv;
    acc.x = hs.x * w; acc.y = hs.y * w; acc.z = hs.z * w; acc.w = hs.w * w;
  }
  const int len0 = fill[v];
  const int len = len0 < REVC ? len0 : REVC;
  const size_t beg = (size_t)v * REVC;
  for (int e = half; e < len; e += 2) {
    const int i = rev[beg + e];
    const float sc = dinv[i] * dv;
    const float4 h4 = *((const float4*)(H + (size_t)i * DH) + q);
    acc.x += h4.x * sc; acc.y += h4.y * sc;
    acc.z += h4.z * sc; acc.w += h4.w * sc;
  }
  // combine halves (both halves end up with the full sum)
  acc.x += __shfl_xor(acc.x, 32);
  acc.y += __shfl_xor(acc.y, 32);
  acc.z += __shfl_xor(acc.z, 32);
  acc.w += __shfl_xor(acc.w, 32);

  const float4 b4 = *((const float4*)bias + q);
  float4 t;
  t.x = tanhf(acc.x + b4.x);
  t.y = tanhf(acc.y + b4.y);
  t.z = tanhf(acc.z + b4.z);
  t.w = tanhf(acc.w + b4.w);

  if (!HEAD) {
    if (half == 0) *((float4*)(Xout + (size_t)v * DH) + q) = t;
  } else {
    // half h computes outs 4h..4h+3: po[oo] = sum_j t[j]*Wout[4q+j][4h+oo]
    const float4 w0 = *(const float4*)&Wout[(4 * q + 0) * DOUT + 4 * half];
    const float4 w1 = *(const float4*)&Wout[(4 * q + 1) * DOUT + 4 * half];
    const float4 w2 = *(const float4*)&Wout[(4 * q + 2) * DOUT + 4 * half];
    const float4 w3 = *(const float4*)&Wout[(4 * q + 3) * DOUT + 4 * half];
    float4 po;
    po.x = t.x * w0.x + t.y * w1.x + t.z * w2.x + t.w * w3.x;
    po.y = t.x * w0.y + t.y * w1.y + t.z * w2.y + t.w * w3.y;
    po.z = t.x * w0.z + t.y * w1.z + t.z * w2.z + t.w * w3.z;
    po.w = t.x * w0.w + t.y * w1.w + t.z * w2.w + t.w * w3.w;
#pragma unroll
    for (int off = 16; off >= 1; off >>= 1) {
      po.x += __shfl_xor(po.x, off);
      po.y += __shfl_xor(po.y, off);
      po.z += __shfl_xor(po.z, off);
      po.w += __shfl_xor(po.w, off);
    }
    if (q == 0) {
      const float4 bo = *(const float4*)&bout[4 * half];
      po.x += bo.x; po.y += bo.y; po.z += bo.z; po.w += bo.w;
      *(float4*)(Xout + (size_t)v * DOUT + 4 * half) = po;
    }
  }
}

// ---------------------------------------------------------------- launch
extern "C" void kernel_launch(void* const* d_in, const int* in_sizes, int n_in,
                              void* d_out, int out_size, void* d_ws, size_t ws_size,
                              hipStream_t stream) {
  const float* obs  = (const float*)d_in[0];
  const float* W1   = (const float*)d_in[1];
  const float* b1   = (const float*)d_in[2];
  const float* W2   = (const float*)d_in[3];
  const float* b2   = (const float*)d_in[4];
  const float* Wout = (const float*)d_in[5];
  const float* bout = (const float*)d_in[6];
  float* out = (float*)d_out;

  char* p = (char*)d_ws;
  auto carve = [&](size_t bytes) {
    void* r = (void*)p;
    p += (bytes + 255) / 256 * 256;
    return r;
  };
  float* h    = (float*)carve((size_t)NN * DH * 4);       // 67 MB
  float* x1   = (float*)carve((size_t)NN * DH * 4);       // 67 MB
  int*   rev  = (int*)carve((size_t)NN * REVC * 4);       // 50 MB
  int*   fill = (int*)carve((size_t)NN * 4);
  float* dinv = (float*)carve((size_t)NN * 4);

  hipMemsetAsync(fill, 0, (size_t)NN * 4, stream);

  // graph build: knn + direct reverse-adjacency scatter
  knn_kernel<<<BATCHES * 8, 256, 0, stream>>>(obs, fill, rev);

  // layer 1: h = obs @ W1 (+ dinv epilogue) ; x1 = tanh(agg + b1)
  gemm_kernel<DIN, true><<<NN / 32, 256, 0, stream>>>(obs, W1, h, fill, dinv);
  agg_kernel<false><<<NN * 64 / 256, 256, 0, stream>>>(
      h, fill, rev, dinv, b1, nullptr, nullptr, x1);

  // layer 2: h = x1 @ W2 ; out = tanh(agg + b2) @ Wout + bout  (fused head)
  gemm_kernel<DH, false><<<NN / 32, 256, 0, stream>>>(x1, W2, h, nullptr, nullptr);
  agg_kernel<true><<<NN * 64 / 256, 256, 0, stream>>>(
      h, fill, rev, dinv, b2, Wout, bout, out);
}